// Round 1
// baseline (1705.306 us; speedup 1.0000x reference)
//
#include <hip/hip_runtime.h>
#include <math.h>

// ---------------------------------------------------------------------------
// GraphClassifiction: conv1d(k=3)+relu x2 -> l2norm gram -> powers/fusion ->
// global-max normalize -> 1x1 conv + BN(train) x2 -> sigmoid -> crop mean
// All fp32. Outputs: [normal_scores(128*32), a_v(640*32*32), a_t, a_fused]
// ---------------------------------------------------------------------------

__device__ __forceinline__ float4 ld4(const float* p) {
    return *reinterpret_cast<const float4*>(p);
}

// Pack wv (32, Cin, 3) -> wP[o][c4][k][r] so conv inner loop gets 3 float4
// loads at immediate offsets 0/16/32B from one address.
__global__ void pack_w_kernel(const float* __restrict__ src,
                              float* __restrict__ dst, int Cin) {
    int idx = blockIdx.x * 256 + threadIdx.x;
    int total = 32 * Cin * 3;
    if (idx >= total) return;
    int r = idx & 3;
    int k = (idx >> 2) % 3;
    int rest = idx / 12;            // = o*(Cin/4) + c4
    int c4n = Cin >> 2;
    int c4 = rest % c4n;
    int o  = rest / c4n;
    int c = c4 * 4 + r;
    dst[idx] = src[(o * Cin + c) * 3 + k];
}

// Conv1d k=3 pad=1 over time (T=32) + bias + relu.
// x: (B, 32, Cin) row-major; y: (B, 32, 32).
// One wave computes 4 outputs (same b,t; o..o+3), lanes split the K dim.
__global__ __launch_bounds__(256) void conv_kernel(
    const float* __restrict__ x, const float* __restrict__ wP,
    const float* __restrict__ bias, float* __restrict__ y, int Cin) {
    int bid  = blockIdx.x;          // B*32*2 blocks
    int half = bid & 1;
    int t    = (bid >> 1) & 31;
    int b    = bid >> 6;
    int wave = threadIdx.x >> 6;
    int lane = threadIdx.x & 63;
    int o0   = half * 16 + wave * 4;
    const float* xrow = x + (size_t)(b * 32 + t) * Cin;
    int c4n = Cin >> 2;
    float acc[4] = {0.f, 0.f, 0.f, 0.f};
    for (int c = lane * 4; c < Cin; c += 256) {
        float4 v0 = make_float4(0.f, 0.f, 0.f, 0.f);
        float4 v2 = make_float4(0.f, 0.f, 0.f, 0.f);
        if (t > 0)  v0 = ld4(xrow - Cin + c);   // k=0 reads row t-1 (zero pad)
        float4 v1 = ld4(xrow + c);              // k=1 reads row t
        if (t < 31) v2 = ld4(xrow + Cin + c);   // k=2 reads row t+1
        int c4 = c >> 2;
#pragma unroll
        for (int j = 0; j < 4; ++j) {
            const float* wp = wP + (size_t)((o0 + j) * c4n + c4) * 12;
            float4 w0 = ld4(wp);
            float4 w1 = ld4(wp + 4);
            float4 w2 = ld4(wp + 8);
            float a = acc[j];
            a = fmaf(v0.x, w0.x, a); a = fmaf(v0.y, w0.y, a);
            a = fmaf(v0.z, w0.z, a); a = fmaf(v0.w, w0.w, a);
            a = fmaf(v1.x, w1.x, a); a = fmaf(v1.y, w1.y, a);
            a = fmaf(v1.z, w1.z, a); a = fmaf(v1.w, w1.w, a);
            a = fmaf(v2.x, w2.x, a); a = fmaf(v2.y, w2.y, a);
            a = fmaf(v2.z, w2.z, a); a = fmaf(v2.w, w2.w, a);
            acc[j] = a;
        }
    }
#pragma unroll
    for (int j = 0; j < 4; ++j)
        for (int off = 1; off < 64; off <<= 1)
            acc[j] += __shfl_xor(acc[j], off);
    if (lane == 0) {
        size_t base = (size_t)(b * 32 + t) * 32 + o0;
        y[base + 0] = fmaxf(acc[0] + bias[o0 + 0], 0.f);
        y[base + 1] = fmaxf(acc[1] + bias[o0 + 1], 0.f);
        y[base + 2] = fmaxf(acc[2] + bias[o0 + 2], 0.f);
        y[base + 3] = fmaxf(acc[3] + bias[o0 + 3], 0.f);
    }
}

// Per-b: l2norm rows, a_v/a_t gram + relu, powers + fusion, relu, global max.
__global__ __launch_bounds__(256) void s2_kernel(
    const float* __restrict__ fv, const float* __restrict__ ft,
    const float* __restrict__ fuse, float* __restrict__ out_av,
    float* __restrict__ out_at, float* __restrict__ out_af,
    unsigned int* __restrict__ maxslot) {
    int b = blockIdx.x, tid = threadIdx.x;
    __shared__ float Fv[32][33], Ft[32][33], inv[64], wmax[4];
#pragma unroll
    for (int e = 0; e < 4; ++e) {
        int idx = tid + 256 * e;
        int i = idx >> 5, j = idx & 31;
        Fv[i][j] = fv[b * 1024 + idx];
        Ft[i][j] = ft[b * 1024 + idx];
    }
    __syncthreads();
    if (tid < 64) {
        int i = tid & 31;
        float s = 0.f;
        if (tid < 32) {
            for (int c = 0; c < 32; ++c) { float v = Fv[i][c]; s = fmaf(v, v, s); }
        } else {
            for (int c = 0; c < 32; ++c) { float v = Ft[i][c]; s = fmaf(v, v, s); }
        }
        inv[tid] = 1.0f / fmaxf(sqrtf(s), 1e-12f);
    }
    __syncthreads();
    float fa[16];
#pragma unroll
    for (int q = 0; q < 16; ++q) fa[q] = fuse[q];
    float lmax = 0.f;
#pragma unroll
    for (int e = 0; e < 4; ++e) {
        int idx = tid + 256 * e;
        int i = idx >> 5, j = idx & 31;
        float dv = 0.f, dt_ = 0.f;
        for (int c = 0; c < 32; ++c) {
            dv  = fmaf(Fv[i][c], Fv[j][c], dv);
            dt_ = fmaf(Ft[i][c], Ft[j][c], dt_);
        }
        float av = fmaxf(dv  * inv[i] * inv[j], 0.f);
        float at = fmaxf(dt_ * inv[32 + i] * inv[32 + j], 0.f);
        out_av[b * 1024 + idx] = av;
        out_at[b * 1024 + idx] = at;
        float pv0 = (i == j) ? 1.f : 0.f;
        float pv1 = av, pv2 = av * av, pv3 = pv2 * av;
        float pt0 = pv0;  // same identity mask
        float pt1 = at, pt2 = at * at, pt3 = pt2 * at;
        float af = 0.f;
        af += (fa[0] * pv0 + fa[4] * pv1 + fa[8]  * pv2 + fa[12] * pv3) * pt0;
        af += (fa[1] * pv0 + fa[5] * pv1 + fa[9]  * pv2 + fa[13] * pv3) * pt1;
        af += (fa[2] * pv0 + fa[6] * pv1 + fa[10] * pv2 + fa[14] * pv3) * pt2;
        af += (fa[3] * pv0 + fa[7] * pv1 + fa[11] * pv2 + fa[15] * pv3) * pt3;
        float r = fmaxf(af, 0.f);
        out_af[b * 1024 + idx] = r;   // pre-normalization; scaled in s3
        lmax = fmaxf(lmax, r);
    }
    for (int off = 1; off < 64; off <<= 1)
        lmax = fmaxf(lmax, __shfl_xor(lmax, off));
    if ((tid & 63) == 0) wmax[tid >> 6] = lmax;
    __syncthreads();
    if (tid == 0) {
        float m = fmaxf(fmaxf(wmax[0], wmax[1]), fmaxf(wmax[2], wmax[3]));
        atomicMax(maxslot, __float_as_uint(m));  // valid: all values >= 0
    }
}

// Scale a_fused by 1/(max+0.01) in place; x1 = w1 @ x + b1; BN1 partial sums.
__global__ __launch_bounds__(256) void s3_kernel(
    float* __restrict__ af, const float* __restrict__ w1,
    const float* __restrict__ b1, float* __restrict__ x1,
    float* __restrict__ scal) {
    int b = blockIdx.x, tid = threadIdx.x;
    __shared__ float A[32][33];
    float inv = 1.0f / (__uint_as_float(((const unsigned int*)scal)[0]) + 0.01f);
#pragma unroll
    for (int e = 0; e < 4; ++e) {
        int idx = tid + 256 * e;
        float v = af[b * 1024 + idx] * inv;
        af[b * 1024 + idx] = v;      // final a_fused output
        A[idx >> 5][idx & 31] = v;
    }
    __syncthreads();
    if (tid < 64) {
        int o = tid >> 5, l = tid & 31;
        float s = b1[o];
        for (int c = 0; c < 32; ++c) s = fmaf(w1[o * 32 + c], A[l][c], s);
        x1[(size_t)(b * 2 + o) * 32 + l] = s;
        float s1 = s, s2 = s * s;
        for (int off = 1; off < 32; off <<= 1) {  // stays within 32-lane halves
            s1 += __shfl_xor(s1, off);
            s2 += __shfl_xor(s2, off);
        }
        if (l == 0) {
            atomicAdd(&scal[1 + o], s1);
            atomicAdd(&scal[3 + o], s2);
        }
    }
}

// BN1 finalize -> relu -> x2 = w2@h1 + b2; BN2 partial sums.
__global__ __launch_bounds__(256) void s4_kernel(
    const float* __restrict__ x1, const float* __restrict__ g1,
    const float* __restrict__ be1, const float* __restrict__ w2,
    const float* __restrict__ b2, float* __restrict__ x2,
    float* __restrict__ scal) {
    int idx = blockIdx.x * 256 + threadIdx.x;   // 20480 = 640*32
    const float N = 20480.f;
    float mu0 = scal[1] / N, mu1 = scal[2] / N;
    float va0 = scal[3] / N - mu0 * mu0, va1 = scal[4] / N - mu1 * mu1;
    float rs0 = rsqrtf(va0 + 1e-5f), rs1 = rsqrtf(va1 + 1e-5f);
    int b = idx >> 5, l = idx & 31;
    float h0 = fmaxf((x1[(size_t)(b * 2 + 0) * 32 + l] - mu0) * rs0 * g1[0] + be1[0], 0.f);
    float h1 = fmaxf((x1[(size_t)(b * 2 + 1) * 32 + l] - mu1) * rs1 * g1[1] + be1[1], 0.f);
    float v = w2[0] * h0 + w2[1] * h1 + b2[0];
    x2[idx] = v;
    float s1 = v, s2 = v * v;
    for (int off = 1; off < 64; off <<= 1) {
        s1 += __shfl_xor(s1, off);
        s2 += __shfl_xor(s2, off);
    }
    __shared__ float ps[4][2];
    int lane = threadIdx.x & 63, w = threadIdx.x >> 6;
    if (lane == 0) { ps[w][0] = s1; ps[w][1] = s2; }
    __syncthreads();
    if (threadIdx.x == 0) {
        atomicAdd(&scal[5], ps[0][0] + ps[1][0] + ps[2][0] + ps[3][0]);
        atomicAdd(&scal[6], ps[0][1] + ps[1][1] + ps[2][1] + ps[3][1]);
    }
}

// BN2 -> relu -> sigmoid(w3*h2+b3) -> mean over 5 crops.
__global__ __launch_bounds__(256) void s5_kernel(
    const float* __restrict__ x2, const float* __restrict__ g2,
    const float* __restrict__ be2, const float* __restrict__ w3,
    const float* __restrict__ b3, float* __restrict__ ns,
    const float* __restrict__ scal) {
    int idx = blockIdx.x * 256 + threadIdx.x;   // 4096 = 128*32
    const float N = 20480.f;
    float mu = scal[5] / N;
    float var = scal[6] / N - mu * mu;
    float rs = rsqrtf(var + 1e-5f);
    int bb = idx >> 5, t = idx & 31;
    float s = 0.f;
#pragma unroll
    for (int crop = 0; crop < 5; ++crop) {
        int b = bb * 5 + crop;
        float h = fmaxf((x2[b * 32 + t] - mu) * rs * g2[0] + be2[0], 0.f);
        float z = w3[0] * h + b3[0];
        s += 1.f / (1.f + expf(-z));
    }
    ns[idx] = s * 0.2f;
}

extern "C" void kernel_launch(void* const* d_in, const int* in_sizes, int n_in,
                              void* d_out, int out_size, void* d_ws, size_t ws_size,
                              hipStream_t stream) {
    const float* v_feat = (const float*)d_in[0];
    const float* t_feat = (const float*)d_in[1];
    const float* wv  = (const float*)d_in[2];
    const float* bv  = (const float*)d_in[3];
    const float* wt  = (const float*)d_in[4];
    const float* bt  = (const float*)d_in[5];
    const float* fuse= (const float*)d_in[6];
    const float* w1  = (const float*)d_in[7];
    const float* b1  = (const float*)d_in[8];
    const float* g1  = (const float*)d_in[9];
    const float* be1 = (const float*)d_in[10];
    const float* w2  = (const float*)d_in[11];
    const float* b2  = (const float*)d_in[12];
    const float* g2  = (const float*)d_in[13];
    const float* be2 = (const float*)d_in[14];
    const float* w3  = (const float*)d_in[15];
    const float* b3  = (const float*)d_in[16];

    float* ws   = (float*)d_ws;
    float* scal = ws;                       // [0]=max(uint), [1..4]=BN1 s/ss, [5..6]=BN2
    float* wvP  = ws + 16;                  // 196608
    float* wtP  = wvP + 196608;             // 73728
    float* fv   = wtP + 73728;              // 655360
    float* ft   = fv + 655360;              // 655360
    float* x1   = ft + 655360;              // 40960
    float* x2   = x1 + 40960;               // 20480

    float* out_ns = (float*)d_out;          // 4096
    float* out_av = out_ns + 4096;          // 655360
    float* out_at = out_av + 655360;        // 655360
    float* out_af = out_at + 655360;        // 655360

    hipMemsetAsync(scal, 0, 16 * sizeof(float), stream);
    pack_w_kernel<<<768, 256, 0, stream>>>(wv, wvP, 2048);
    pack_w_kernel<<<288, 256, 0, stream>>>(wt, wtP, 768);
    conv_kernel<<<640 * 32 * 2, 256, 0, stream>>>(v_feat, wvP, bv, fv, 2048);
    conv_kernel<<<640 * 32 * 2, 256, 0, stream>>>(t_feat, wtP, bt, ft, 768);
    s2_kernel<<<640, 256, 0, stream>>>(fv, ft, fuse, out_av, out_at, out_af,
                                       (unsigned int*)scal);
    s3_kernel<<<640, 256, 0, stream>>>(out_af, w1, b1, x1, scal);
    s4_kernel<<<80, 256, 0, stream>>>(x1, g1, be1, w2, b2, x2, scal);
    s5_kernel<<<16, 256, 0, stream>>>(x2, g2, be2, w3, b3, out_ns, scal);
}

// Round 2
// 456.297 us; speedup vs baseline: 3.7373x; 3.7373x over previous
//
#include <hip/hip_runtime.h>
#include <math.h>

// ---------------------------------------------------------------------------
// GraphClassifiction: conv1d(k=3)+relu x2 -> l2norm gram -> powers/fusion ->
// global-max normalize -> 1x1 conv + BN(train) x2 -> sigmoid -> crop mean
// All fp32. Outputs: [normal_scores(128*32), a_v(640*32*32), a_t, a_fused]
//
// R2: conv rebuilt as LDS-tiled GEMM. One block = one batch (t-pad is
// batch-local), 4 waves split the K (channel) dim, 4t x 4o register tile,
// 5 vector LDS reads per 48 FMAs -> VALU-bound instead of L2-bound.
// ---------------------------------------------------------------------------

// Pack w (32, Cin, 3) -> wP[c][k][o] so the conv's LDS stage is a linear copy
// and compute reads are contiguous float4 across o.
__global__ void pack_w_kernel(const float* __restrict__ src,
                              float* __restrict__ dst, int Cin) {
    int idx = blockIdx.x * 256 + threadIdx.x;
    int total = 32 * Cin * 3;
    if (idx >= total) return;
    int o = idx & 31;
    int k = (idx >> 5) % 3;
    int c = idx / 96;
    dst[idx] = src[(o * Cin + c) * 3 + k];
}

// Conv1d k=3 pad=1 over time (T=32) + bias + relu, GEMM-tiled.
// x: (B, 32, Cin) row-major; y: (B, 32, 32). One block per batch b.
// LDS x_sh[c][tt] (tt = t+1, 34 used, stride 44: 16B-aligned rows, low
// conflict), w_sh[c][k][o] (stride 96). Wave w handles chunk channels
// [w*16, w*16+16); partials reduced through LDS at the end.
__global__ __launch_bounds__(256, 4) void conv_gemm_kernel(
    const float* __restrict__ x, const float* __restrict__ wP,
    const float* __restrict__ bias, float* __restrict__ y, int Cin) {
    int b = blockIdx.x;
    int tid = threadIdx.x;
    int wave = tid >> 6, lane = tid & 63;
    int t0 = (lane >> 3) * 4;   // 0..28
    int o0 = (lane & 7) * 4;    // 0..28
    __shared__ float smem[64 * 44 + 64 * 96];   // 2816 + 6144 floats = 35840 B
    float* x_sh = smem;
    float* w_sh = smem + 64 * 44;
    float acc[4][4] = {{0.f}};
    const float* xb = x + (size_t)b * 32 * Cin;
    int nchunk = Cin >> 6;
    for (int ch = 0; ch < nchunk; ++ch) {
        __syncthreads();
        int c0 = ch << 6;
        // stage x chunk (32 t x 64 c), transposed into [c][t+1]
#pragma unroll
        for (int e = 0; e < 8; ++e) {
            int idx = tid + 256 * e;
            int t = idx >> 6, c = idx & 63;
            x_sh[c * 44 + t + 1] = xb[t * Cin + c0 + c];
        }
        if (tid < 64) { x_sh[tid * 44 + 0] = 0.f; x_sh[tid * 44 + 33] = 0.f; }
        // stage w chunk: linear copy of 6144 floats
        const float4* wsrc = (const float4*)(wP + (size_t)c0 * 96);
        float4* wdst = (float4*)w_sh;
#pragma unroll
        for (int e = 0; e < 6; ++e) wdst[tid + 256 * e] = wsrc[tid + 256 * e];
        __syncthreads();
        const float* xr = x_sh + (wave * 16) * 44 + t0;   // tt=t0 -> x[t0-1]
        const float* wr = w_sh + (wave * 16) * 96 + o0;
#pragma unroll 2
        for (int ci = 0; ci < 16; ++ci) {
            float4 xa = *(const float4*)(xr);        // x[t0-1 .. t0+2]
            float2 xc = *(const float2*)(xr + 4);    // x[t0+3 .. t0+4]
            float xv[6] = {xa.x, xa.y, xa.z, xa.w, xc.x, xc.y};
            float4 w0 = *(const float4*)(wr);        // k=0, o0..o0+3
            float4 w1 = *(const float4*)(wr + 32);   // k=1
            float4 w2 = *(const float4*)(wr + 64);   // k=2
            float wk0[4] = {w0.x, w0.y, w0.z, w0.w};
            float wk1[4] = {w1.x, w1.y, w1.z, w1.w};
            float wk2[4] = {w2.x, w2.y, w2.z, w2.w};
#pragma unroll
            for (int i = 0; i < 4; ++i) {
#pragma unroll
                for (int j = 0; j < 4; ++j) {
                    float a = acc[i][j];
                    a = fmaf(xv[i],     wk0[j], a);
                    a = fmaf(xv[i + 1], wk1[j], a);
                    a = fmaf(xv[i + 2], wk2[j], a);
                    acc[i][j] = a;
                }
            }
            xr += 44; wr += 96;
        }
    }
    // reduce 4 per-wave partials through LDS
    __syncthreads();
    float* red = smem;   // 4096 floats
#pragma unroll
    for (int i = 0; i < 4; ++i)
#pragma unroll
        for (int j = 0; j < 4; ++j)
            red[wave * 1024 + (t0 + i) * 32 + o0 + j] = acc[i][j];
    __syncthreads();
#pragma unroll
    for (int e = 0; e < 4; ++e) {
        int out = tid + 256 * e;
        float s = red[out] + red[1024 + out] + red[2048 + out] + red[3072 + out];
        y[(size_t)b * 1024 + out] = fmaxf(s + bias[out & 31], 0.f);
    }
}

// Per-b: l2norm rows, a_v/a_t gram + relu, powers + fusion, relu, global max.
__global__ __launch_bounds__(256) void s2_kernel(
    const float* __restrict__ fv, const float* __restrict__ ft,
    const float* __restrict__ fuse, float* __restrict__ out_av,
    float* __restrict__ out_at, float* __restrict__ out_af,
    unsigned int* __restrict__ maxslot) {
    int b = blockIdx.x, tid = threadIdx.x;
    __shared__ float Fv[32][33], Ft[32][33], inv[64], wmax[4];
#pragma unroll
    for (int e = 0; e < 4; ++e) {
        int idx = tid + 256 * e;
        int i = idx >> 5, j = idx & 31;
        Fv[i][j] = fv[b * 1024 + idx];
        Ft[i][j] = ft[b * 1024 + idx];
    }
    __syncthreads();
    if (tid < 64) {
        int i = tid & 31;
        float s = 0.f;
        if (tid < 32) {
            for (int c = 0; c < 32; ++c) { float v = Fv[i][c]; s = fmaf(v, v, s); }
        } else {
            for (int c = 0; c < 32; ++c) { float v = Ft[i][c]; s = fmaf(v, v, s); }
        }
        inv[tid] = 1.0f / fmaxf(sqrtf(s), 1e-12f);
    }
    __syncthreads();
    float fa[16];
#pragma unroll
    for (int q = 0; q < 16; ++q) fa[q] = fuse[q];
    float lmax = 0.f;
#pragma unroll
    for (int e = 0; e < 4; ++e) {
        int idx = tid + 256 * e;
        int i = idx >> 5, j = idx & 31;
        float dv = 0.f, dt_ = 0.f;
        for (int c = 0; c < 32; ++c) {
            dv  = fmaf(Fv[i][c], Fv[j][c], dv);
            dt_ = fmaf(Ft[i][c], Ft[j][c], dt_);
        }
        float av = fmaxf(dv  * inv[i] * inv[j], 0.f);
        float at = fmaxf(dt_ * inv[32 + i] * inv[32 + j], 0.f);
        out_av[b * 1024 + idx] = av;
        out_at[b * 1024 + idx] = at;
        float pv0 = (i == j) ? 1.f : 0.f;
        float pv1 = av, pv2 = av * av, pv3 = pv2 * av;
        float pt1 = at, pt2 = at * at, pt3 = pt2 * at;
        float af = 0.f;
        af += (fa[0] * pv0 + fa[4] * pv1 + fa[8]  * pv2 + fa[12] * pv3) * pv0;
        af += (fa[1] * pv0 + fa[5] * pv1 + fa[9]  * pv2 + fa[13] * pv3) * pt1;
        af += (fa[2] * pv0 + fa[6] * pv1 + fa[10] * pv2 + fa[14] * pv3) * pt2;
        af += (fa[3] * pv0 + fa[7] * pv1 + fa[11] * pv2 + fa[15] * pv3) * pt3;
        float r = fmaxf(af, 0.f);
        out_af[b * 1024 + idx] = r;   // pre-normalization; scaled in s3
        lmax = fmaxf(lmax, r);
    }
    for (int off = 1; off < 64; off <<= 1)
        lmax = fmaxf(lmax, __shfl_xor(lmax, off));
    if ((tid & 63) == 0) wmax[tid >> 6] = lmax;
    __syncthreads();
    if (tid == 0) {
        float m = fmaxf(fmaxf(wmax[0], wmax[1]), fmaxf(wmax[2], wmax[3]));
        atomicMax(maxslot, __float_as_uint(m));  // valid: all values >= 0
    }
}

// Scale a_fused by 1/(max+0.01) in place; x1 = w1 @ x + b1; BN1 partial sums.
__global__ __launch_bounds__(256) void s3_kernel(
    float* __restrict__ af, const float* __restrict__ w1,
    const float* __restrict__ b1, float* __restrict__ x1,
    float* __restrict__ scal) {
    int b = blockIdx.x, tid = threadIdx.x;
    __shared__ float A[32][33];
    float inv = 1.0f / (__uint_as_float(((const unsigned int*)scal)[0]) + 0.01f);
#pragma unroll
    for (int e = 0; e < 4; ++e) {
        int idx = tid + 256 * e;
        float v = af[b * 1024 + idx] * inv;
        af[b * 1024 + idx] = v;      // final a_fused output
        A[idx >> 5][idx & 31] = v;
    }
    __syncthreads();
    if (tid < 64) {
        int o = tid >> 5, l = tid & 31;
        float s = b1[o];
        for (int c = 0; c < 32; ++c) s = fmaf(w1[o * 32 + c], A[l][c], s);
        x1[(size_t)(b * 2 + o) * 32 + l] = s;
        float s1 = s, s2 = s * s;
        for (int off = 1; off < 32; off <<= 1) {  // stays within 32-lane halves
            s1 += __shfl_xor(s1, off);
            s2 += __shfl_xor(s2, off);
        }
        if (l == 0) {
            atomicAdd(&scal[1 + o], s1);
            atomicAdd(&scal[3 + o], s2);
        }
    }
}

// BN1 finalize -> relu -> x2 = w2@h1 + b2; BN2 partial sums.
__global__ __launch_bounds__(256) void s4_kernel(
    const float* __restrict__ x1, const float* __restrict__ g1,
    const float* __restrict__ be1, const float* __restrict__ w2,
    const float* __restrict__ b2, float* __restrict__ x2,
    float* __restrict__ scal) {
    int idx = blockIdx.x * 256 + threadIdx.x;   // 20480 = 640*32
    const float N = 20480.f;
    float mu0 = scal[1] / N, mu1 = scal[2] / N;
    float va0 = scal[3] / N - mu0 * mu0, va1 = scal[4] / N - mu1 * mu1;
    float rs0 = rsqrtf(va0 + 1e-5f), rs1 = rsqrtf(va1 + 1e-5f);
    int b = idx >> 5, l = idx & 31;
    float h0 = fmaxf((x1[(size_t)(b * 2 + 0) * 32 + l] - mu0) * rs0 * g1[0] + be1[0], 0.f);
    float h1 = fmaxf((x1[(size_t)(b * 2 + 1) * 32 + l] - mu1) * rs1 * g1[1] + be1[1], 0.f);
    float v = w2[0] * h0 + w2[1] * h1 + b2[0];
    x2[idx] = v;
    float s1 = v, s2 = v * v;
    for (int off = 1; off < 64; off <<= 1) {
        s1 += __shfl_xor(s1, off);
        s2 += __shfl_xor(s2, off);
    }
    __shared__ float ps[4][2];
    int lane = threadIdx.x & 63, w = threadIdx.x >> 6;
    if (lane == 0) { ps[w][0] = s1; ps[w][1] = s2; }
    __syncthreads();
    if (threadIdx.x == 0) {
        atomicAdd(&scal[5], ps[0][0] + ps[1][0] + ps[2][0] + ps[3][0]);
        atomicAdd(&scal[6], ps[0][1] + ps[1][1] + ps[2][1] + ps[3][1]);
    }
}

// BN2 -> relu -> sigmoid(w3*h2+b3) -> mean over 5 crops.
__global__ __launch_bounds__(256) void s5_kernel(
    const float* __restrict__ x2, const float* __restrict__ g2,
    const float* __restrict__ be2, const float* __restrict__ w3,
    const float* __restrict__ b3, float* __restrict__ ns,
    const float* __restrict__ scal) {
    int idx = blockIdx.x * 256 + threadIdx.x;   // 4096 = 128*32
    const float N = 20480.f;
    float mu = scal[5] / N;
    float var = scal[6] / N - mu * mu;
    float rs = rsqrtf(var + 1e-5f);
    int bb = idx >> 5, t = idx & 31;
    float s = 0.f;
#pragma unroll
    for (int crop = 0; crop < 5; ++crop) {
        int b = bb * 5 + crop;
        float h = fmaxf((x2[b * 32 + t] - mu) * rs * g2[0] + be2[0], 0.f);
        float z = w3[0] * h + b3[0];
        s += 1.f / (1.f + expf(-z));
    }
    ns[idx] = s * 0.2f;
}

extern "C" void kernel_launch(void* const* d_in, const int* in_sizes, int n_in,
                              void* d_out, int out_size, void* d_ws, size_t ws_size,
                              hipStream_t stream) {
    const float* v_feat = (const float*)d_in[0];
    const float* t_feat = (const float*)d_in[1];
    const float* wv  = (const float*)d_in[2];
    const float* bv  = (const float*)d_in[3];
    const float* wt  = (const float*)d_in[4];
    const float* bt  = (const float*)d_in[5];
    const float* fuse= (const float*)d_in[6];
    const float* w1  = (const float*)d_in[7];
    const float* b1  = (const float*)d_in[8];
    const float* g1  = (const float*)d_in[9];
    const float* be1 = (const float*)d_in[10];
    const float* w2  = (const float*)d_in[11];
    const float* b2  = (const float*)d_in[12];
    const float* g2  = (const float*)d_in[13];
    const float* be2 = (const float*)d_in[14];
    const float* w3  = (const float*)d_in[15];
    const float* b3  = (const float*)d_in[16];

    float* ws   = (float*)d_ws;
    float* scal = ws;                       // [0]=max(uint), [1..4]=BN1 s/ss, [5..6]=BN2
    float* wvP  = ws + 16;                  // 196608
    float* wtP  = wvP + 196608;             // 73728
    float* fv   = wtP + 73728;              // 655360
    float* ft   = fv + 655360;              // 655360
    float* x1   = ft + 655360;              // 40960
    float* x2   = x1 + 40960;               // 20480

    float* out_ns = (float*)d_out;          // 4096
    float* out_av = out_ns + 4096;          // 655360
    float* out_at = out_av + 655360;        // 655360
    float* out_af = out_at + 655360;        // 655360

    hipMemsetAsync(scal, 0, 16 * sizeof(float), stream);
    pack_w_kernel<<<768, 256, 0, stream>>>(wv, wvP, 2048);
    pack_w_kernel<<<288, 256, 0, stream>>>(wt, wtP, 768);
    conv_gemm_kernel<<<640, 256, 0, stream>>>(v_feat, wvP, bv, fv, 2048);
    conv_gemm_kernel<<<640, 256, 0, stream>>>(t_feat, wtP, bt, ft, 768);
    s2_kernel<<<640, 256, 0, stream>>>(fv, ft, fuse, out_av, out_at, out_af,
                                       (unsigned int*)scal);
    s3_kernel<<<640, 256, 0, stream>>>(out_af, w1, b1, x1, scal);
    s4_kernel<<<80, 256, 0, stream>>>(x1, g1, be1, w2, b2, x2, scal);
    s5_kernel<<<16, 256, 0, stream>>>(x2, g2, be2, w3, b3, out_ns, scal);
}

// Round 3
// 424.353 us; speedup vs baseline: 4.0186x; 1.0753x over previous
//
#include <hip/hip_runtime.h>
#include <math.h>

// ---------------------------------------------------------------------------
// GraphClassifiction: conv1d(k=3)+relu x2 -> l2norm gram -> powers/fusion ->
// global-max normalize -> 1x1 conv + BN(train) x2 -> sigmoid -> crop mean
// All fp32. Outputs: [normal_scores(128*32), a_v(640*32*32), a_t, a_fused]
//
// R3: conv occupancy fix. Split-K x2 per batch (grid 2560, both convs in one
// dispatch), chunk=32ch -> LDS 16.9KB -> 8 blocks/CU. Partials via fp32
// atomicAdd (2 adds, commutative -> deterministic); bias+relu fused into s2.
// Pack kernel read-coalesced; scal/fv/ft zeroing folded in.
// ---------------------------------------------------------------------------

// Pack w (32, Cin, 3) -> wP[c][k][o]; also zero scal + partial buffers.
__global__ __launch_bounds__(256) void pack_kernel(
    const float* __restrict__ wv, const float* __restrict__ wt,
    float* __restrict__ wvP, float* __restrict__ wtP,
    float* __restrict__ scal, float* __restrict__ zbuf, int nz) {
    int gid = blockIdx.x * 256 + threadIdx.x;
    if (gid < 16) scal[gid] = 0.f;
    for (int i = gid; i < nz; i += gridDim.x * 256) zbuf[i] = 0.f;
    const int NV = 32 * 2048 * 3;   // 196608
    const int NT = 32 * 768 * 3;    // 73728
    if (gid < NV) {
        int o = gid / 6144, rem = gid % 6144;
        int c = rem / 3, k = rem % 3;
        wvP[c * 96 + k * 32 + o] = wv[gid];
    } else if (gid < NV + NT) {
        int s = gid - NV;
        int o = s / 2304, rem = s % 2304;
        int c = rem / 3, k = rem % 3;
        wtP[c * 96 + k * 32 + o] = wt[s];
    }
}

// Conv1d k=3 pad=1 (T=32), GEMM-tiled, split-K x2.
// Blocks 0..1279: visual (Cin 2048), 1280..2559: text (Cin 768).
// Per block: half the channels; raw partial accumulated into y via atomicAdd.
// LDS: x_sh[c][tt] stride 36 (tt=t+1, 34 used), w_sh[c][k][o] stride 96.
__global__ __launch_bounds__(256, 8) void conv_kernel(
    const float* __restrict__ xv, const float* __restrict__ wvP,
    const float* __restrict__ xt, const float* __restrict__ wtP,
    float* __restrict__ yv, float* __restrict__ yt) {
    int bid = blockIdx.x;
    const float* x; const float* wP; float* y; int Cin;
    if (bid < 1280) { x = xv; wP = wvP; y = yv; Cin = 2048; }
    else { bid -= 1280; x = xt; wP = wtP; y = yt; Cin = 768; }
    int Ch = Cin >> 1;
    int b = bid >> 1, half = bid & 1;
    int c0g = half * Ch;
    int nchunk = Ch >> 5;
    int tid = threadIdx.x, wave = tid >> 6, lane = tid & 63;
    int t0 = (lane >> 3) * 4;   // 0..28
    int o0 = (lane & 7) * 4;    // 0..28
    __shared__ float smem[32 * 36 + 32 * 96];   // 4224 floats = 16896 B
    float* x_sh = smem;
    float* w_sh = smem + 32 * 36;
    float acc[4][4] = {{0.f}};
    const float* xb = x + (size_t)b * 32 * Cin + c0g;
    const float* wb = wP + (size_t)c0g * 96;
    int ts = tid >> 3, i4 = (tid & 7) * 4;   // staging: row t, 4 channels
    for (int ch = 0; ch < nchunk; ++ch) {
        int c0 = ch << 5;
        __syncthreads();
        float4 xq = *(const float4*)(xb + (size_t)ts * Cin + c0 + i4);
        x_sh[(i4 + 0) * 36 + ts + 1] = xq.x;
        x_sh[(i4 + 1) * 36 + ts + 1] = xq.y;
        x_sh[(i4 + 2) * 36 + ts + 1] = xq.z;
        x_sh[(i4 + 3) * 36 + ts + 1] = xq.w;
        if (tid < 32) { x_sh[tid * 36] = 0.f; x_sh[tid * 36 + 33] = 0.f; }
        const float4* wsrc = (const float4*)(wb + (size_t)c0 * 96);
        float4* wdst = (float4*)w_sh;
#pragma unroll
        for (int e = 0; e < 3; ++e) wdst[tid + 256 * e] = wsrc[tid + 256 * e];
        __syncthreads();
        const float* xr = x_sh + (wave * 8) * 36 + t0;   // tt=t0 -> x[t0-1]
        const float* wr = w_sh + (wave * 8) * 96 + o0;
#pragma unroll
        for (int ci = 0; ci < 8; ++ci) {
            float4 xa = *(const float4*)(xr);        // x[t0-1 .. t0+2]
            float2 xc = *(const float2*)(xr + 4);    // x[t0+3 .. t0+4]
            float xvv[6] = {xa.x, xa.y, xa.z, xa.w, xc.x, xc.y};
            float4 w0 = *(const float4*)(wr);        // k=0
            float4 w1 = *(const float4*)(wr + 32);   // k=1
            float4 w2 = *(const float4*)(wr + 64);   // k=2
            float wk0[4] = {w0.x, w0.y, w0.z, w0.w};
            float wk1[4] = {w1.x, w1.y, w1.z, w1.w};
            float wk2[4] = {w2.x, w2.y, w2.z, w2.w};
#pragma unroll
            for (int i = 0; i < 4; ++i) {
#pragma unroll
                for (int j = 0; j < 4; ++j) {
                    float a = acc[i][j];
                    a = fmaf(xvv[i],     wk0[j], a);
                    a = fmaf(xvv[i + 1], wk1[j], a);
                    a = fmaf(xvv[i + 2], wk2[j], a);
                    acc[i][j] = a;
                }
            }
            xr += 36; wr += 96;
        }
    }
    // reduce 4 per-wave partials through LDS, then atomic-accumulate
    __syncthreads();
    float* red = smem;   // 4224 floats available >= 4096
#pragma unroll
    for (int i = 0; i < 4; ++i)
#pragma unroll
        for (int j = 0; j < 4; ++j)
            red[wave * 1024 + (t0 + i) * 32 + o0 + j] = acc[i][j];
    __syncthreads();
#pragma unroll
    for (int e = 0; e < 4; ++e) {
        int out = tid + 256 * e;
        float s = red[out] + red[1024 + out] + red[2048 + out] + red[3072 + out];
        atomicAdd(&y[(size_t)b * 1024 + out], s);
    }
}

// Per-b: bias+relu, l2norm rows, gram + relu, powers + fusion, global max.
__global__ __launch_bounds__(256) void s2_kernel(
    const float* __restrict__ fvp, const float* __restrict__ ftp,
    const float* __restrict__ bv, const float* __restrict__ bt,
    const float* __restrict__ fuse, float* __restrict__ out_av,
    float* __restrict__ out_at, float* __restrict__ out_af,
    unsigned int* __restrict__ maxslot) {
    int b = blockIdx.x, tid = threadIdx.x;
    __shared__ float Fv[32][33], Ft[32][33], inv[64], wmax[4];
#pragma unroll
    for (int e = 0; e < 4; ++e) {
        int idx = tid + 256 * e;
        int i = idx >> 5, j = idx & 31;
        Fv[i][j] = fmaxf(fvp[b * 1024 + idx] + bv[j], 0.f);
        Ft[i][j] = fmaxf(ftp[b * 1024 + idx] + bt[j], 0.f);
    }
    __syncthreads();
    {
        int row = tid >> 3, cg = (tid & 7) * 4;
        float sv = 0.f, st = 0.f;
#pragma unroll
        for (int q = 0; q < 4; ++q) {
            float v = Fv[row][cg + q]; sv = fmaf(v, v, sv);
            float u = Ft[row][cg + q]; st = fmaf(u, u, st);
        }
        sv += __shfl_xor(sv, 1); sv += __shfl_xor(sv, 2); sv += __shfl_xor(sv, 4);
        st += __shfl_xor(st, 1); st += __shfl_xor(st, 2); st += __shfl_xor(st, 4);
        if ((tid & 7) == 0) {
            // 1/max(||x||,1e-12) == rsqrt(max(ss,1e-24)) exactly at these scales
            inv[row]      = rsqrtf(fmaxf(sv, 1e-24f));
            inv[32 + row] = rsqrtf(fmaxf(st, 1e-24f));
        }
    }
    __syncthreads();
    float fa[16];
#pragma unroll
    for (int q = 0; q < 16; ++q) fa[q] = fuse[q];
    float lmax = 0.f;
#pragma unroll
    for (int e = 0; e < 4; ++e) {
        int idx = tid + 256 * e;
        int i = idx >> 5, j = idx & 31;
        float dv = 0.f, dt_ = 0.f;
        for (int c = 0; c < 32; ++c) {
            dv  = fmaf(Fv[i][c], Fv[j][c], dv);
            dt_ = fmaf(Ft[i][c], Ft[j][c], dt_);
        }
        float av = fmaxf(dv  * inv[i] * inv[j], 0.f);
        float at = fmaxf(dt_ * inv[32 + i] * inv[32 + j], 0.f);
        out_av[b * 1024 + idx] = av;
        out_at[b * 1024 + idx] = at;
        float pv0 = (i == j) ? 1.f : 0.f;
        float pv1 = av, pv2 = av * av, pv3 = pv2 * av;
        float pt1 = at, pt2 = at * at, pt3 = pt2 * at;
        float af = 0.f;
        af += (fa[0] * pv0 + fa[4] * pv1 + fa[8]  * pv2 + fa[12] * pv3) * pv0;
        af += (fa[1] * pv0 + fa[5] * pv1 + fa[9]  * pv2 + fa[13] * pv3) * pt1;
        af += (fa[2] * pv0 + fa[6] * pv1 + fa[10] * pv2 + fa[14] * pv3) * pt2;
        af += (fa[3] * pv0 + fa[7] * pv1 + fa[11] * pv2 + fa[15] * pv3) * pt3;
        float r = fmaxf(af, 0.f);
        out_af[b * 1024 + idx] = r;   // pre-normalization; scaled in s3
        lmax = fmaxf(lmax, r);
    }
    for (int off = 1; off < 64; off <<= 1)
        lmax = fmaxf(lmax, __shfl_xor(lmax, off));
    if ((tid & 63) == 0) wmax[tid >> 6] = lmax;
    __syncthreads();
    if (tid == 0) {
        float m = fmaxf(fmaxf(wmax[0], wmax[1]), fmaxf(wmax[2], wmax[3]));
        atomicMax(maxslot, __float_as_uint(m));  // valid: all values >= 0
    }
}

// Scale a_fused by 1/(max+0.01) in place; x1 = w1 @ x + b1; BN1 partial sums.
__global__ __launch_bounds__(256) void s3_kernel(
    float* __restrict__ af, const float* __restrict__ w1,
    const float* __restrict__ b1, float* __restrict__ x1,
    float* __restrict__ scal) {
    int b = blockIdx.x, tid = threadIdx.x;
    __shared__ float A[32][33];
    float inv = 1.0f / (__uint_as_float(((const unsigned int*)scal)[0]) + 0.01f);
#pragma unroll
    for (int e = 0; e < 4; ++e) {
        int idx = tid + 256 * e;
        float v = af[b * 1024 + idx] * inv;
        af[b * 1024 + idx] = v;      // final a_fused output
        A[idx >> 5][idx & 31] = v;
    }
    __syncthreads();
    if (tid < 64) {
        int o = tid >> 5, l = tid & 31;
        float s = b1[o];
        for (int c = 0; c < 32; ++c) s = fmaf(w1[o * 32 + c], A[l][c], s);
        x1[(size_t)(b * 2 + o) * 32 + l] = s;
        float s1 = s, s2 = s * s;
        for (int off = 1; off < 32; off <<= 1) {  // stays within 32-lane halves
            s1 += __shfl_xor(s1, off);
            s2 += __shfl_xor(s2, off);
        }
        if (l == 0) {
            atomicAdd(&scal[1 + o], s1);
            atomicAdd(&scal[3 + o], s2);
        }
    }
}

// BN1 finalize -> relu -> x2 = w2@h1 + b2; BN2 partial sums.
__global__ __launch_bounds__(256) void s4_kernel(
    const float* __restrict__ x1, const float* __restrict__ g1,
    const float* __restrict__ be1, const float* __restrict__ w2,
    const float* __restrict__ b2, float* __restrict__ x2,
    float* __restrict__ scal) {
    int idx = blockIdx.x * 256 + threadIdx.x;   // 20480 = 640*32
    const float N = 20480.f;
    float mu0 = scal[1] / N, mu1 = scal[2] / N;
    float va0 = scal[3] / N - mu0 * mu0, va1 = scal[4] / N - mu1 * mu1;
    float rs0 = rsqrtf(va0 + 1e-5f), rs1 = rsqrtf(va1 + 1e-5f);
    int b = idx >> 5, l = idx & 31;
    float h0 = fmaxf((x1[(size_t)(b * 2 + 0) * 32 + l] - mu0) * rs0 * g1[0] + be1[0], 0.f);
    float h1 = fmaxf((x1[(size_t)(b * 2 + 1) * 32 + l] - mu1) * rs1 * g1[1] + be1[1], 0.f);
    float v = w2[0] * h0 + w2[1] * h1 + b2[0];
    x2[idx] = v;
    float s1 = v, s2 = v * v;
    for (int off = 1; off < 64; off <<= 1) {
        s1 += __shfl_xor(s1, off);
        s2 += __shfl_xor(s2, off);
    }
    __shared__ float ps[4][2];
    int lane = threadIdx.x & 63, w = threadIdx.x >> 6;
    if (lane == 0) { ps[w][0] = s1; ps[w][1] = s2; }
    __syncthreads();
    if (threadIdx.x == 0) {
        atomicAdd(&scal[5], ps[0][0] + ps[1][0] + ps[2][0] + ps[3][0]);
        atomicAdd(&scal[6], ps[0][1] + ps[1][1] + ps[2][1] + ps[3][1]);
    }
}

// BN2 -> relu -> sigmoid(w3*h2+b3) -> mean over 5 crops.
__global__ __launch_bounds__(256) void s5_kernel(
    const float* __restrict__ x2, const float* __restrict__ g2,
    const float* __restrict__ be2, const float* __restrict__ w3,
    const float* __restrict__ b3, float* __restrict__ ns,
    const float* __restrict__ scal) {
    int idx = blockIdx.x * 256 + threadIdx.x;   // 4096 = 128*32
    const float N = 20480.f;
    float mu = scal[5] / N;
    float var = scal[6] / N - mu * mu;
    float rs = rsqrtf(var + 1e-5f);
    int bb = idx >> 5, t = idx & 31;
    float s = 0.f;
#pragma unroll
    for (int crop = 0; crop < 5; ++crop) {
        int b = bb * 5 + crop;
        float h = fmaxf((x2[b * 32 + t] - mu) * rs * g2[0] + be2[0], 0.f);
        float z = w3[0] * h + b3[0];
        s += 1.f / (1.f + expf(-z));
    }
    ns[idx] = s * 0.2f;
}

extern "C" void kernel_launch(void* const* d_in, const int* in_sizes, int n_in,
                              void* d_out, int out_size, void* d_ws, size_t ws_size,
                              hipStream_t stream) {
    const float* v_feat = (const float*)d_in[0];
    const float* t_feat = (const float*)d_in[1];
    const float* wv  = (const float*)d_in[2];
    const float* bv  = (const float*)d_in[3];
    const float* wt  = (const float*)d_in[4];
    const float* bt  = (const float*)d_in[5];
    const float* fuse= (const float*)d_in[6];
    const float* w1  = (const float*)d_in[7];
    const float* b1  = (const float*)d_in[8];
    const float* g1  = (const float*)d_in[9];
    const float* be1 = (const float*)d_in[10];
    const float* w2  = (const float*)d_in[11];
    const float* b2  = (const float*)d_in[12];
    const float* g2  = (const float*)d_in[13];
    const float* be2 = (const float*)d_in[14];
    const float* w3  = (const float*)d_in[15];
    const float* b3  = (const float*)d_in[16];

    float* ws   = (float*)d_ws;
    float* scal = ws;                       // [0]=max(uint), [1..4]=BN1, [5..6]=BN2
    float* wvP  = ws + 16;                  // 196608
    float* wtP  = wvP + 196608;             // 73728
    float* fv   = wtP + 73728;              // 655360 (conv partial accumulators)
    float* ft   = fv + 655360;              // 655360
    float* x1   = ft + 655360;              // 40960
    float* x2   = x1 + 40960;               // 20480

    float* out_ns = (float*)d_out;          // 4096
    float* out_av = out_ns + 4096;          // 655360
    float* out_at = out_av + 655360;        // 655360
    float* out_af = out_at + 655360;        // 655360

    pack_kernel<<<1056, 256, 0, stream>>>(wv, wt, wvP, wtP, scal, fv, 2 * 655360);
    conv_kernel<<<2560, 256, 0, stream>>>(v_feat, wvP, t_feat, wtP, fv, ft);
    s2_kernel<<<640, 256, 0, stream>>>(fv, ft, bv, bt, fuse, out_av, out_at,
                                       out_af, (unsigned int*)scal);
    s3_kernel<<<640, 256, 0, stream>>>(out_af, w1, b1, x1, scal);
    s4_kernel<<<80, 256, 0, stream>>>(x1, g1, be1, w2, b2, x2, scal);
    s5_kernel<<<16, 256, 0, stream>>>(x2, g2, be2, w3, b3, out_ns, scal);
}

// Round 5
// 396.436 us; speedup vs baseline: 4.3016x; 1.0704x over previous
//
#include <hip/hip_runtime.h>
#include <hip/hip_bf16.h>
#include <math.h>

// ---------------------------------------------------------------------------
// GraphClassifiction: conv1d(k=3)+relu x2 -> l2norm gram -> powers/fusion ->
// global-max normalize -> 1x1 conv + BN(train) x2 -> sigmoid -> crop mean
// Outputs: [normal_scores(128*32), a_v(640*32*32), a_t, a_fused]
//
// R5: fix R4's packed-weight overlap. Each (slice,tap) B-block is 32x32 =
// 1024 elems; block stride now 2048 ushorts (hi[1024] | lo[1024]).
// R4 had hi/lo at +0/+512 -> o>=16 hi overwrote o<16 lo. MFMA layouts
// (m89-verified): A[m=lane&15][k=quad*8+j], B[n=lane&15][k=quad*8+j],
// D[row=quad*4+reg][col=lane&15].
// ---------------------------------------------------------------------------

typedef __attribute__((ext_vector_type(8))) short short8;
typedef __attribute__((ext_vector_type(4))) float f32x4;

#define XROW 132   // ushorts per LDS tile row: 128 data + 4 pad

__device__ __forceinline__ unsigned short f2bf(float f) {
    __hip_bfloat16 h = __float2bfloat16(f);
    return *reinterpret_cast<unsigned short*>(&h);
}
__device__ __forceinline__ float bf2f(unsigned short u) {
    return __uint_as_float(((unsigned int)u) << 16);
}
__device__ __forceinline__ short8 lds_frag(const unsigned short* p) {
    union { uint2 u2[2]; short8 s; } r;
    r.u2[0] = *reinterpret_cast<const uint2*>(p);
    r.u2[1] = *reinterpret_cast<const uint2*>(p + 4);
    return r.s;
}
__device__ __forceinline__ short8 glb_frag(const unsigned short* p) {
    union { uint4 u; short8 s; } r;
    r.u = *reinterpret_cast<const uint4*>(p);
    return r.s;
}

// Pack w (32, Cin, 3) fp32 -> B-fragment blocks, bf16 hi/lo.
// Block per (slice s, tap k): 2048 ushorts = hi[o*32+c'] | lo[o*32+c'].
// Also zeroes scal.
__global__ __launch_bounds__(256) void pack_kernel(
    const float* __restrict__ wv, const float* __restrict__ wt,
    unsigned short* __restrict__ wvpk, unsigned short* __restrict__ wtpk,
    float* __restrict__ scal) {
    int gid = blockIdx.x * 256 + threadIdx.x;
    if (gid < 16) scal[gid] = 0.f;
    const int NV = 196608, NT = 73728;   // 32*2048*3, 32*768*3
    if (gid < NV) {
        int o = gid / 6144, rem = gid % 6144;
        int c = rem / 3, k = rem % 3;
        int s = c >> 5, cp = c & 31;
        float f = wv[gid];
        unsigned short h = f2bf(f);
        unsigned short l = f2bf(f - bf2f(h));
        int base = (s * 3 + k) * 2048 + o * 32 + cp;
        wvpk[base] = h;
        wvpk[base + 1024] = l;
    } else if (gid < NV + NT) {
        int g = gid - NV;
        int o = g / 2304, rem = g % 2304;
        int c = rem / 3, k = rem % 3;
        int s = c >> 5, cp = c & 31;
        float f = wt[g];
        unsigned short h = f2bf(f);
        unsigned short l = f2bf(f - bf2f(h));
        int base = (s * 3 + k) * 2048 + o * 32 + cp;
        wtpk[base] = h;
        wtpk[base + 1024] = l;
    }
}

// One conv (visual or text) for one batch b. 4 waves: wave -> (tm,tn) 16x16
// output tile. K streamed in 128-ch chunks staged to LDS as hi/lo bf16 tiles
// [row 0..33][c], row = t+1, rows 0/33 zero (conv pad). Tap k = A-read at
// row+k. Accumulates hh in acc0, hl+lh in acc1 (shorter dep chains).
__device__ __forceinline__ void conv_phase(
    const float* __restrict__ xb, int Cin,
    const unsigned short* __restrict__ wpk,
    unsigned short* hiT, unsigned short* loT,
    float* __restrict__ yout, int tid, int wave, int lane) {
    __syncthreads();   // previous phase's LDS readers done
    if (tid < XROW) {
        hiT[tid] = 0; hiT[33 * XROW + tid] = 0;
        loT[tid] = 0; loT[33 * XROW + tid] = 0;
    }
    f32x4 acc0 = {0.f, 0.f, 0.f, 0.f};
    f32x4 acc1 = {0.f, 0.f, 0.f, 0.f};
    int tm = wave & 1, tn = wave >> 1;
    int m = lane & 15, quad = lane >> 4;
    int c4 = tid & 31, tg = tid >> 5;
    int nchunk = Cin >> 7;
    for (int ch = 0; ch < nchunk; ++ch) {
        int c0 = ch << 7;
        __syncthreads();   // previous chunk's readers done
#pragma unroll
        for (int pass = 0; pass < 4; ++pass) {
            int t = tg + (pass << 3);
            const float4 xq = *reinterpret_cast<const float4*>(
                xb + (size_t)t * Cin + c0 + (c4 << 2));
            unsigned short h0 = f2bf(xq.x), h1 = f2bf(xq.y);
            unsigned short h2 = f2bf(xq.z), h3 = f2bf(xq.w);
            unsigned short l0 = f2bf(xq.x - bf2f(h0));
            unsigned short l1 = f2bf(xq.y - bf2f(h1));
            unsigned short l2 = f2bf(xq.z - bf2f(h2));
            unsigned short l3 = f2bf(xq.w - bf2f(h3));
            int widx = (t + 1) * XROW + (c4 << 2);
            *reinterpret_cast<uint2*>(hiT + widx) =
                make_uint2(h0 | ((unsigned int)h1 << 16), h2 | ((unsigned int)h3 << 16));
            *reinterpret_cast<uint2*>(loT + widx) =
                make_uint2(l0 | ((unsigned int)l1 << 16), l2 | ((unsigned int)l3 << 16));
        }
        __syncthreads();
        int sbase = c0 >> 5;
        int arow0 = (tm << 4) + m;
        int bofs = ((tn << 4) + m) * 32 + (quad << 3);
#pragma unroll
        for (int sl = 0; sl < 4; ++sl) {
            int acol = (sl << 5) + (quad << 3);
            const unsigned short* bbase = wpk + (size_t)(sbase + sl) * 6144 + bofs;
#pragma unroll
            for (int k = 0; k < 3; ++k) {
                short8 Ah = lds_frag(hiT + (arow0 + k) * XROW + acol);
                short8 Al = lds_frag(loT + (arow0 + k) * XROW + acol);
                short8 Bh = glb_frag(bbase + k * 2048);
                short8 Bl = glb_frag(bbase + k * 2048 + 1024);
                acc0 = __builtin_amdgcn_mfma_f32_16x16x32_bf16(Ah, Bh, acc0, 0, 0, 0);
                acc1 = __builtin_amdgcn_mfma_f32_16x16x32_bf16(Ah, Bl, acc1, 0, 0, 0);
                acc1 = __builtin_amdgcn_mfma_f32_16x16x32_bf16(Al, Bh, acc1, 0, 0, 0);
            }
        }
    }
    int ocol = (tn << 4) + m;
#pragma unroll
    for (int r = 0; r < 4; ++r) {
        int t = (tm << 4) + (quad << 2) + r;
        yout[t * 32 + ocol] = acc0[r] + acc1[r];
    }
}

__global__ __launch_bounds__(256, 4) void conv_mfma_kernel(
    const float* __restrict__ xv, const unsigned short* __restrict__ wvpk,
    const float* __restrict__ xt, const unsigned short* __restrict__ wtpk,
    float* __restrict__ yv, float* __restrict__ yt) {
    __shared__ unsigned short hiT[34 * XROW], loT[34 * XROW];
    int b = blockIdx.x, tid = threadIdx.x;
    int wave = tid >> 6, lane = tid & 63;
    conv_phase(xv + (size_t)b * 32 * 2048, 2048, wvpk, hiT, loT,
               yv + (size_t)b * 1024, tid, wave, lane);
    conv_phase(xt + (size_t)b * 32 * 768, 768, wtpk, hiT, loT,
               yt + (size_t)b * 1024, tid, wave, lane);
}

// Per-b: bias+relu, l2norm rows, gram + relu, powers + fusion, global max.
__global__ __launch_bounds__(256) void s2_kernel(
    const float* __restrict__ fvp, const float* __restrict__ ftp,
    const float* __restrict__ bv, const float* __restrict__ bt,
    const float* __restrict__ fuse, float* __restrict__ out_av,
    float* __restrict__ out_at, float* __restrict__ out_af,
    unsigned int* __restrict__ maxslot) {
    int b = blockIdx.x, tid = threadIdx.x;
    __shared__ float Fv[32][33], Ft[32][33], inv[64], wmax[4];
#pragma unroll
    for (int e = 0; e < 4; ++e) {
        int idx = tid + 256 * e;
        int i = idx >> 5, j = idx & 31;
        Fv[i][j] = fmaxf(fvp[b * 1024 + idx] + bv[j], 0.f);
        Ft[i][j] = fmaxf(ftp[b * 1024 + idx] + bt[j], 0.f);
    }
    __syncthreads();
    {
        int row = tid >> 3, cg = (tid & 7) * 4;
        float sv = 0.f, st = 0.f;
#pragma unroll
        for (int q = 0; q < 4; ++q) {
            float v = Fv[row][cg + q]; sv = fmaf(v, v, sv);
            float u = Ft[row][cg + q]; st = fmaf(u, u, st);
        }
        sv += __shfl_xor(sv, 1); sv += __shfl_xor(sv, 2); sv += __shfl_xor(sv, 4);
        st += __shfl_xor(st, 1); st += __shfl_xor(st, 2); st += __shfl_xor(st, 4);
        if ((tid & 7) == 0) {
            inv[row]      = rsqrtf(fmaxf(sv, 1e-24f));
            inv[32 + row] = rsqrtf(fmaxf(st, 1e-24f));
        }
    }
    __syncthreads();
    float fa[16];
#pragma unroll
    for (int q = 0; q < 16; ++q) fa[q] = fuse[q];
    float lmax = 0.f;
#pragma unroll
    for (int e = 0; e < 4; ++e) {
        int idx = tid + 256 * e;
        int i = idx >> 5, j = idx & 31;
        float dv = 0.f, dt_ = 0.f;
        for (int c = 0; c < 32; ++c) {
            dv  = fmaf(Fv[i][c], Fv[j][c], dv);
            dt_ = fmaf(Ft[i][c], Ft[j][c], dt_);
        }
        float av = fmaxf(dv  * inv[i] * inv[j], 0.f);
        float at = fmaxf(dt_ * inv[32 + i] * inv[32 + j], 0.f);
        out_av[b * 1024 + idx] = av;
        out_at[b * 1024 + idx] = at;
        float pv0 = (i == j) ? 1.f : 0.f;
        float pv1 = av, pv2 = av * av, pv3 = pv2 * av;
        float pt1 = at, pt2 = at * at, pt3 = pt2 * at;
        float af = 0.f;
        af += (fa[0] * pv0 + fa[4] * pv1 + fa[8]  * pv2 + fa[12] * pv3) * pv0;
        af += (fa[1] * pv0 + fa[5] * pv1 + fa[9]  * pv2 + fa[13] * pv3) * pt1;
        af += (fa[2] * pv0 + fa[6] * pv1 + fa[10] * pv2 + fa[14] * pv3) * pt2;
        af += (fa[3] * pv0 + fa[7] * pv1 + fa[11] * pv2 + fa[15] * pv3) * pt3;
        float r = fmaxf(af, 0.f);
        out_af[b * 1024 + idx] = r;   // pre-normalization; scaled in s3
        lmax = fmaxf(lmax, r);
    }
    for (int off = 1; off < 64; off <<= 1)
        lmax = fmaxf(lmax, __shfl_xor(lmax, off));
    if ((tid & 63) == 0) wmax[tid >> 6] = lmax;
    __syncthreads();
    if (tid == 0) {
        float mx = fmaxf(fmaxf(wmax[0], wmax[1]), fmaxf(wmax[2], wmax[3]));
        atomicMax(maxslot, __float_as_uint(mx));  // valid: all values >= 0
    }
}

// Scale a_fused by 1/(max+0.01) in place; x1 = w1 @ x + b1; BN1 partial sums.
__global__ __launch_bounds__(256) void s3_kernel(
    float* __restrict__ af, const float* __restrict__ w1,
    const float* __restrict__ b1, float* __restrict__ x1,
    float* __restrict__ scal) {
    int b = blockIdx.x, tid = threadIdx.x;
    __shared__ float A[32][33];
    float inv = 1.0f / (__uint_as_float(((const unsigned int*)scal)[0]) + 0.01f);
#pragma unroll
    for (int e = 0; e < 4; ++e) {
        int idx = tid + 256 * e;
        float v = af[b * 1024 + idx] * inv;
        af[b * 1024 + idx] = v;      // final a_fused output
        A[idx >> 5][idx & 31] = v;
    }
    __syncthreads();
    if (tid < 64) {
        int o = tid >> 5, l = tid & 31;
        float s = b1[o];
        for (int c = 0; c < 32; ++c) s = fmaf(w1[o * 32 + c], A[l][c], s);
        x1[(size_t)(b * 2 + o) * 32 + l] = s;
        float s1 = s, s2 = s * s;
        for (int off = 1; off < 32; off <<= 1) {
            s1 += __shfl_xor(s1, off);
            s2 += __shfl_xor(s2, off);
        }
        if (l == 0) {
            atomicAdd(&scal[1 + o], s1);
            atomicAdd(&scal[3 + o], s2);
        }
    }
}

// BN1 finalize -> relu -> x2 = w2@h1 + b2; BN2 partial sums.
__global__ __launch_bounds__(256) void s4_kernel(
    const float* __restrict__ x1, const float* __restrict__ g1,
    const float* __restrict__ be1, const float* __restrict__ w2,
    const float* __restrict__ b2, float* __restrict__ x2,
    float* __restrict__ scal) {
    int idx = blockIdx.x * 256 + threadIdx.x;   // 20480 = 640*32
    const float N = 20480.f;
    float mu0 = scal[1] / N, mu1 = scal[2] / N;
    float va0 = scal[3] / N - mu0 * mu0, va1 = scal[4] / N - mu1 * mu1;
    float rs0 = rsqrtf(va0 + 1e-5f), rs1 = rsqrtf(va1 + 1e-5f);
    int b = idx >> 5, l = idx & 31;
    float h0 = fmaxf((x1[(size_t)(b * 2 + 0) * 32 + l] - mu0) * rs0 * g1[0] + be1[0], 0.f);
    float h1 = fmaxf((x1[(size_t)(b * 2 + 1) * 32 + l] - mu1) * rs1 * g1[1] + be1[1], 0.f);
    float v = w2[0] * h0 + w2[1] * h1 + b2[0];
    x2[idx] = v;
    float s1 = v, s2 = v * v;
    for (int off = 1; off < 64; off <<= 1) {
        s1 += __shfl_xor(s1, off);
        s2 += __shfl_xor(s2, off);
    }
    __shared__ float ps[4][2];
    int lane = threadIdx.x & 63, w = threadIdx.x >> 6;
    if (lane == 0) { ps[w][0] = s1; ps[w][1] = s2; }
    __syncthreads();
    if (threadIdx.x == 0) {
        atomicAdd(&scal[5], ps[0][0] + ps[1][0] + ps[2][0] + ps[3][0]);
        atomicAdd(&scal[6], ps[0][1] + ps[1][1] + ps[2][1] + ps[3][1]);
    }
}

// BN2 -> relu -> sigmoid(w3*h2+b3) -> mean over 5 crops.
__global__ __launch_bounds__(256) void s5_kernel(
    const float* __restrict__ x2, const float* __restrict__ g2,
    const float* __restrict__ be2, const float* __restrict__ w3,
    const float* __restrict__ b3, float* __restrict__ ns,
    const float* __restrict__ scal) {
    int idx = blockIdx.x * 256 + threadIdx.x;   // 4096 = 128*32
    const float N = 20480.f;
    float mu = scal[5] / N;
    float var = scal[6] / N - mu * mu;
    float rs = rsqrtf(var + 1e-5f);
    int bb = idx >> 5, t = idx & 31;
    float s = 0.f;
#pragma unroll
    for (int crop = 0; crop < 5; ++crop) {
        int b = bb * 5 + crop;
        float h = fmaxf((x2[b * 32 + t] - mu) * rs * g2[0] + be2[0], 0.f);
        float z = w3[0] * h + b3[0];
        s += 1.f / (1.f + expf(-z));
    }
    ns[idx] = s * 0.2f;
}

extern "C" void kernel_launch(void* const* d_in, const int* in_sizes, int n_in,
                              void* d_out, int out_size, void* d_ws, size_t ws_size,
                              hipStream_t stream) {
    const float* v_feat = (const float*)d_in[0];
    const float* t_feat = (const float*)d_in[1];
    const float* wv  = (const float*)d_in[2];
    const float* bv  = (const float*)d_in[3];
    const float* wt  = (const float*)d_in[4];
    const float* bt  = (const float*)d_in[5];
    const float* fuse= (const float*)d_in[6];
    const float* w1  = (const float*)d_in[7];
    const float* b1  = (const float*)d_in[8];
    const float* g1  = (const float*)d_in[9];
    const float* be1 = (const float*)d_in[10];
    const float* w2  = (const float*)d_in[11];
    const float* b2  = (const float*)d_in[12];
    const float* g2  = (const float*)d_in[13];
    const float* be2 = (const float*)d_in[14];
    const float* w3  = (const float*)d_in[15];
    const float* b3  = (const float*)d_in[16];

    float* ws   = (float*)d_ws;
    float* scal = ws;                       // [0]=max(uint), [1..4]=BN1, [5..6]=BN2
    unsigned short* wvpk = (unsigned short*)(ws + 16);          // 393216 ushorts
    unsigned short* wtpk = (unsigned short*)(ws + 16 + 196608); // 147456 ushorts
    float* fv   = ws + 16 + 196608 + 73728; // 655360
    float* ft   = fv + 655360;              // 655360
    float* x1   = ft + 655360;              // 40960
    float* x2   = x1 + 40960;               // 20480

    float* out_ns = (float*)d_out;          // 4096
    float* out_av = out_ns + 4096;          // 655360
    float* out_at = out_av + 655360;        // 655360
    float* out_af = out_at + 655360;        // 655360

    pack_kernel<<<1056, 256, 0, stream>>>(wv, wt, wvpk, wtpk, scal);
    conv_mfma_kernel<<<640, 256, 0, stream>>>(v_feat, wvpk, t_feat, wtpk, fv, ft);
    s2_kernel<<<640, 256, 0, stream>>>(fv, ft, bv, bt, fuse, out_av, out_at,
                                       out_af, (unsigned int*)scal);
    s3_kernel<<<640, 256, 0, stream>>>(out_af, w1, b1, x1, scal);
    s4_kernel<<<80, 256, 0, stream>>>(x1, g1, be1, w2, b2, x2, scal);
    s5_kernel<<<16, 256, 0, stream>>>(x2, g2, be2, w3, b3, out_ns, scal);
}